// Round 1
// baseline (400.470 us; speedup 1.0000x reference)
//
#include <hip/hip_runtime.h>

// TensorTree: B=65536 batch, F=8 leaves, D=2 local dim, R=10 rank, U=32 units.
// out[b,u] = top( pair-tree of leaf contractions ), all fp32.
// Compute-bound on the fp32 VALU (~28.8 GFLOP, no fp32 MFMA on CDNA4).
// Strategy: u is block-uniform -> all weights are wave-uniform scalar loads
// (s_load), VALU does pure FMA. UPT=2 units per thread share each core
// scalar across 2 FMA chains.

#define BB 65536
#define FF 8
#define DD 2
#define RR 10
#define UU 32
#define UPT 2

__device__ __forceinline__ void leaf_contract(
    const float x0, const float x1,   // X[b,f,0], X[b,f,1]
    const float* __restrict__ FM,     // factor_matrices [D,R,F,U]
    int f, int u,
    float c[RR])
{
#pragma unroll
    for (int r = 0; r < RR; ++r) {
        // FM[((d*R + r)*F + f)*U + u]
        float w0 = FM[((0 * RR + r) * FF + f) * UU + u];
        float w1 = FM[((1 * RR + r) * FF + f) * UU + u];
        c[r] = fmaf(x1, w1, x0 * w0);
    }
}

__device__ __forceinline__ void pair_contract(
    const float a[UPT][RR], const float bb[UPT][RR],
    const float* __restrict__ core,   // [R,R,R] as core[(i*R+k)*R+j]
    float con[UPT][RR])
{
#pragma unroll
    for (int t = 0; t < UPT; ++t)
#pragma unroll
        for (int j = 0; j < RR; ++j) con[t][j] = 0.0f;

#pragma unroll
    for (int i = 0; i < RR; ++i) {
#pragma unroll
        for (int k = 0; k < RR; ++k) {
            float prod[UPT];
#pragma unroll
            for (int t = 0; t < UPT; ++t) prod[t] = a[t][i] * bb[t][k];
            const float* __restrict__ crow = core + (i * RR + k) * RR;
#pragma unroll
            for (int j = 0; j < RR; ++j) {
                float cw = crow[j];   // wave-uniform -> scalar load
#pragma unroll
                for (int t = 0; t < UPT; ++t)
                    con[t][j] = fmaf(cw, prod[t], con[t][j]);
            }
        }
    }
}

__global__ __launch_bounds__(256) void tensortree_kernel(
    const float* __restrict__ X,
    const float* __restrict__ core11, const float* __restrict__ core12,
    const float* __restrict__ core13, const float* __restrict__ core14,
    const float* __restrict__ core21, const float* __restrict__ core22,
    const float* __restrict__ FM, const float* __restrict__ MT,
    float* __restrict__ out)
{
    const int b  = blockIdx.x * blockDim.x + threadIdx.x;   // 0..65535
    const int u0 = blockIdx.y * UPT;                        // block-uniform

    // Load X[b, 0..7, 0..1] = 16 contiguous floats as 4x float4.
    float x[FF][DD];
    const float4* xp = reinterpret_cast<const float4*>(X + (size_t)b * (FF * DD));
#pragma unroll
    for (int q = 0; q < 4; ++q) {
        float4 v = xp[q];
        x[q * 2 + 0][0] = v.x; x[q * 2 + 0][1] = v.y;
        x[q * 2 + 1][0] = v.z; x[q * 2 + 1][1] = v.w;
    }

    float cA[UPT][RR], cB[UPT][RR];
    float p1[UPT][RR], p2[UPT][RR], p3[UPT][RR], p4[UPT][RR];
    float q1[UPT][RR], q2[UPT][RR];

    // Level 1+2, left half
#pragma unroll
    for (int t = 0; t < UPT; ++t) {
        leaf_contract(x[0][0], x[0][1], FM, 0, u0 + t, cA[t]);
        leaf_contract(x[1][0], x[1][1], FM, 1, u0 + t, cB[t]);
    }
    pair_contract(cA, cB, core11, p1);
#pragma unroll
    for (int t = 0; t < UPT; ++t) {
        leaf_contract(x[2][0], x[2][1], FM, 2, u0 + t, cA[t]);
        leaf_contract(x[3][0], x[3][1], FM, 3, u0 + t, cB[t]);
    }
    pair_contract(cA, cB, core12, p2);
    pair_contract(p1, p2, core21, q1);

    // Level 1+2, right half
#pragma unroll
    for (int t = 0; t < UPT; ++t) {
        leaf_contract(x[4][0], x[4][1], FM, 4, u0 + t, cA[t]);
        leaf_contract(x[5][0], x[5][1], FM, 5, u0 + t, cB[t]);
    }
    pair_contract(cA, cB, core13, p3);
#pragma unroll
    for (int t = 0; t < UPT; ++t) {
        leaf_contract(x[6][0], x[6][1], FM, 6, u0 + t, cA[t]);
        leaf_contract(x[7][0], x[7][1], FM, 7, u0 + t, cB[t]);
    }
    pair_contract(cA, cB, core14, p4);
    pair_contract(p3, p4, core22, q2);

    // Top: out[b,u] = sum_j (sum_i q1_i * M[i,j]) * q2_j
    float acc[UPT];
#pragma unroll
    for (int t = 0; t < UPT; ++t) acc[t] = 0.0f;
#pragma unroll
    for (int j = 0; j < RR; ++j) {
        float tj[UPT];
#pragma unroll
        for (int t = 0; t < UPT; ++t) tj[t] = 0.0f;
#pragma unroll
        for (int i = 0; i < RR; ++i) {
            float m = MT[i * RR + j];   // wave-uniform
#pragma unroll
            for (int t = 0; t < UPT; ++t) tj[t] = fmaf(q1[t][i], m, tj[t]);
        }
#pragma unroll
        for (int t = 0; t < UPT; ++t) acc[t] = fmaf(tj[t], q2[t][j], acc[t]);
    }

    // out[b*U + u0 .. u0+1], 8B-aligned contiguous -> float2 store
    float2 o;
    o.x = acc[0];
    o.y = acc[1];
    *reinterpret_cast<float2*>(out + (size_t)b * UU + u0) = o;
}

extern "C" void kernel_launch(void* const* d_in, const int* in_sizes, int n_in,
                              void* d_out, int out_size, void* d_ws, size_t ws_size,
                              hipStream_t stream) {
    const float* X      = (const float*)d_in[0];
    const float* core11 = (const float*)d_in[1];
    const float* core12 = (const float*)d_in[2];
    const float* core13 = (const float*)d_in[3];
    const float* core14 = (const float*)d_in[4];
    const float* core21 = (const float*)d_in[5];
    const float* core22 = (const float*)d_in[6];
    const float* FM     = (const float*)d_in[7];
    const float* MT     = (const float*)d_in[8];
    float* out          = (float*)d_out;

    dim3 grid(BB / 256, UU / UPT);   // (256, 16)
    dim3 block(256);
    tensortree_kernel<<<grid, block, 0, stream>>>(
        X, core11, core12, core13, core14, core21, core22, FM, MT, out);
}

// Round 2
// 148.788 us; speedup vs baseline: 2.6916x; 2.6916x over previous
//
#include <hip/hip_runtime.h>

// TensorTree collapsed: out[b,u] is multilinear of degree 8 in the eight
// leaf vectors x_f in R^2, so out[b,u] = sum_{c in {0,1}^8} prod_f x[b,f,c_f] * T_u[c]
// where T_u[c] = tree evaluated on basis vectors (weights only).
// Kernel 1: build T[32][256] in d_ws (tiny). Kernel 2: out = w1^T T_u w2 with
// w1 = (x0 (x) x1 (x) x2 (x) x3), w2 = (x4 (x) x5 (x) x6 (x) x7): 48 muls + 272 FMA
// per (b,u) instead of ~6870 — 21x FLOP reduction vs round-1 kernel.

#define BB 65536
#define FF 8
#define DD 2
#define RR 10
#define UU 32
#define UPT 2   // units per thread in main kernel

// ---------------- kernel 1: precompute T ----------------

__device__ __forceinline__ void pair1(
    const float a[RR], const float b[RR],
    const float* __restrict__ core, float con[RR])
{
#pragma unroll
    for (int j = 0; j < RR; ++j) con[j] = 0.0f;
#pragma unroll
    for (int i = 0; i < RR; ++i) {
#pragma unroll
        for (int k = 0; k < RR; ++k) {
            float prod = a[i] * b[k];
            const float* crow = core + (i * RR + k) * RR;
#pragma unroll
            for (int j = 0; j < RR; ++j)
                con[j] = fmaf(crow[j], prod, con[j]);
        }
    }
}

__global__ __launch_bounds__(256) void precompute_T(
    const float* __restrict__ core11, const float* __restrict__ core12,
    const float* __restrict__ core13, const float* __restrict__ core14,
    const float* __restrict__ core21, const float* __restrict__ core22,
    const float* __restrict__ FM, const float* __restrict__ MT,
    float* __restrict__ T)
{
    const int u = blockIdx.x;      // 0..31
    const int c = threadIdx.x;     // 0..255, bit f = basis index of leaf f

    // leaf vectors on basis inputs: leaf[f][r] = FM[a_f, r, f, u]
    float leaf[FF][RR];
#pragma unroll
    for (int f = 0; f < FF; ++f) {
        const int a = (c >> f) & 1;
#pragma unroll
        for (int r = 0; r < RR; ++r)
            leaf[f][r] = FM[((a * RR + r) * FF + f) * UU + u];
    }

    float p1[RR], p2[RR], p3[RR], p4[RR], q1[RR], q2[RR];
    pair1(leaf[0], leaf[1], core11, p1);
    pair1(leaf[2], leaf[3], core12, p2);
    pair1(leaf[4], leaf[5], core13, p3);
    pair1(leaf[6], leaf[7], core14, p4);
    pair1(p1, p2, core21, q1);
    pair1(p3, p4, core22, q2);

    float val = 0.0f;
#pragma unroll
    for (int i = 0; i < RR; ++i) {
        float r = 0.0f;
#pragma unroll
        for (int j = 0; j < RR; ++j)
            r = fmaf(MT[i * RR + j], q2[j], r);
        val = fmaf(q1[i], r, val);
    }
    // layout: T[u][c], c = q*16 + p  (p = leaves 0..3 bits, q = leaves 4..7 bits)
    T[u * 256 + c] = val;
}

// ---------------- kernel 2: batch evaluation ----------------

__global__ __launch_bounds__(256) void tree_eval(
    const float* __restrict__ X,
    const float* __restrict__ T,
    float* __restrict__ out)
{
    const int b  = blockIdx.x * blockDim.x + threadIdx.x;  // 0..65535
    const int u0 = blockIdx.y * UPT;                       // block-uniform

    // X[b, 0..7, 0..1] = 16 contiguous floats
    float x[FF][2];
    const float4* xp = reinterpret_cast<const float4*>(X + (size_t)b * (FF * DD));
#pragma unroll
    for (int qq = 0; qq < 4; ++qq) {
        float4 v = xp[qq];
        x[qq * 2 + 0][0] = v.x; x[qq * 2 + 0][1] = v.y;
        x[qq * 2 + 1][0] = v.z; x[qq * 2 + 1][1] = v.w;
    }

    // w1[p] = x0[p0]*x1[p1]*x2[p2]*x3[p3], p = p0 | p1<<1 | p2<<2 | p3<<3
    float t01[4], t23[4], t45[4], t67[4];
#pragma unroll
    for (int a1 = 0; a1 < 2; ++a1)
#pragma unroll
        for (int a0 = 0; a0 < 2; ++a0) {
            t01[a1 * 2 + a0] = x[0][a0] * x[1][a1];
            t23[a1 * 2 + a0] = x[2][a0] * x[3][a1];
            t45[a1 * 2 + a0] = x[4][a0] * x[5][a1];
            t67[a1 * 2 + a0] = x[6][a0] * x[7][a1];
        }
    float w1[16], w2[16];
#pragma unroll
    for (int p = 0; p < 16; ++p) {
        w1[p] = t01[p & 3] * t23[p >> 2];
        w2[p] = t45[p & 3] * t67[p >> 2];
    }

    // out[b,u] = sum_q w2[q] * sum_p T[u][q*16+p] * w1[p]
    const float* __restrict__ Ta = T + (u0 + 0) * 256;  // wave-uniform -> s_load
    const float* __restrict__ Tb = T + (u0 + 1) * 256;

    float accA = 0.0f, accB = 0.0f;
#pragma unroll
    for (int q = 0; q < 16; ++q) {
        float sA0 = 0.0f, sA1 = 0.0f, sB0 = 0.0f, sB1 = 0.0f;
#pragma unroll
        for (int p = 0; p < 8; ++p) {
            sA0 = fmaf(Ta[q * 16 + p], w1[p], sA0);
            sB0 = fmaf(Tb[q * 16 + p], w1[p], sB0);
        }
#pragma unroll
        for (int p = 8; p < 16; ++p) {
            sA1 = fmaf(Ta[q * 16 + p], w1[p], sA1);
            sB1 = fmaf(Tb[q * 16 + p], w1[p], sB1);
        }
        accA = fmaf(w2[q], sA0 + sA1, accA);
        accB = fmaf(w2[q], sB0 + sB1, accB);
    }

    float2 o;
    o.x = accA;
    o.y = accB;
    *reinterpret_cast<float2*>(out + (size_t)b * UU + u0) = o;
}

extern "C" void kernel_launch(void* const* d_in, const int* in_sizes, int n_in,
                              void* d_out, int out_size, void* d_ws, size_t ws_size,
                              hipStream_t stream) {
    const float* X      = (const float*)d_in[0];
    const float* core11 = (const float*)d_in[1];
    const float* core12 = (const float*)d_in[2];
    const float* core13 = (const float*)d_in[3];
    const float* core14 = (const float*)d_in[4];
    const float* core21 = (const float*)d_in[5];
    const float* core22 = (const float*)d_in[6];
    const float* FM     = (const float*)d_in[7];
    const float* MT     = (const float*)d_in[8];
    float* out          = (float*)d_out;
    float* T            = (float*)d_ws;   // 32*256*4 = 32 KB

    precompute_T<<<dim3(UU), dim3(256), 0, stream>>>(
        core11, core12, core13, core14, core21, core22, FM, MT, T);

    tree_eval<<<dim3(BB / 256, UU / UPT), dim3(256), 0, stream>>>(X, T, out);
}

// Round 3
// 115.030 us; speedup vs baseline: 3.4814x; 1.2935x over previous
//
#include <hip/hip_runtime.h>

// TensorTree collapsed to multilinear table: out[b,u] = w1(b)^T T_u w2(b),
// w1 = x0(x)x1(x)x2(x)x3, w2 = x4(x)x5(x)x6(x)x7  (16-dim each).
// Round 3:
//  - precompute_T_fast: factorized through the tree (P -> Q -> R1 -> T),
//    task-parallel across 256 threads per unit, LDS-staged. ~52k FMA/u
//    instead of 1.77M (round-2 kernel was 61 us latency-bound serial).
//  - tree_eval: BPT=2 batches x UPT=2 units per thread; the wave-uniform
//    T scalar-load stream is amortized over 2x the FMA.

#define BB 65536
#define FF 8
#define DD 2
#define RR 10
#define UU 32
#define UPT 2
#define BPT 2

// ---------------- kernel 1: precompute T (one block per unit) ----------------

__global__ __launch_bounds__(256) void precompute_T_fast(
    const float* __restrict__ core11, const float* __restrict__ core12,
    const float* __restrict__ core13, const float* __restrict__ core14,
    const float* __restrict__ core21, const float* __restrict__ core22,
    const float* __restrict__ FM, const float* __restrict__ MT,
    float* __restrict__ T)
{
    const int u   = blockIdx.x;    // 0..31
    const int tid = threadIdx.x;   // 0..255

    __shared__ float sLeaf[FF][2][RR];   // [leaf][basis][r]
    __shared__ float sP[4][4][RR];       // [pair][combo(a_lo + 2*a_hi)][j]
    __shared__ float sQ[2][16][RR];      // [side][combo][j]
    __shared__ float sR1[16][RR];        // Q1 . MT

    // Phase 0: leaf basis vectors. leaf[f][a][r] = FM[a, r, f, u]
    if (tid < FF * 2 * RR) {             // 160 tasks
        const int f = tid / (2 * RR);
        const int rem = tid % (2 * RR);
        const int a = rem / RR;
        const int r = rem % RR;
        sLeaf[f][a][r] = FM[((a * RR + r) * FF + f) * UU + u];
    }
    __syncthreads();

    // Phase A: level-1 pairs. 4 pairs x 4 combos x RR j = 160 tasks.
    if (tid < 4 * 4 * RR) {
        const int P   = tid / (4 * RR);        // which pair
        const int rem = tid % (4 * RR);
        const int s   = rem / RR;              // combo: a_lo + 2*a_hi
        const int j   = rem % RR;
        const int fa = 2 * P, fb = 2 * P + 1;
        const int ai = s & 1, bi = s >> 1;
        const float* cp = (P == 0) ? core11 : (P == 1) ? core12
                        : (P == 2) ? core13 : core14;
        float a[RR], b[RR];
#pragma unroll
        for (int i = 0; i < RR; ++i) { a[i] = sLeaf[fa][ai][i]; b[i] = sLeaf[fb][bi][i]; }
        float acc = 0.0f;
#pragma unroll
        for (int i = 0; i < RR; ++i)
#pragma unroll
            for (int k = 0; k < RR; ++k)
                acc = fmaf(a[i] * b[k], cp[(i * RR + k) * RR + j], acc);
        sP[P][s][j] = acc;
    }
    __syncthreads();

    // Phase B: level-2. 2 sides x 16 combos x RR j = 320 tasks.
    for (int t = tid; t < 2 * 16 * RR; t += 256) {
        const int side  = t / (16 * RR);
        const int rem   = t % (16 * RR);
        const int combo = rem / RR;
        const int j     = rem % RR;
        const int pa = side * 2, pb = side * 2 + 1;     // P1,P2 or P3,P4
        const float* cp = side ? core22 : core21;
        float a[RR], b[RR];
#pragma unroll
        for (int i = 0; i < RR; ++i) {
            a[i] = sP[pa][combo & 3][i];
            b[i] = sP[pb][combo >> 2][i];
        }
        float acc = 0.0f;
#pragma unroll
        for (int i = 0; i < RR; ++i)
#pragma unroll
            for (int k = 0; k < RR; ++k)
                acc = fmaf(a[i] * b[k], cp[(i * RR + k) * RR + j], acc);
        sQ[side][combo][j] = acc;
    }
    __syncthreads();

    // Phase C: R1[p][j] = sum_i Q1[p][i] * MT[i][j]. 160 tasks.
    if (tid < 16 * RR) {
        const int p = tid / RR;
        const int j = tid % RR;
        float acc = 0.0f;
#pragma unroll
        for (int i = 0; i < RR; ++i)
            acc = fmaf(sQ[0][p][i], MT[i * RR + j], acc);
        sR1[p][j] = acc;
    }
    __syncthreads();

    // Phase D: T[u][q*16+p] = sum_j R1[p][j] * Q2[q][j]. 256 tasks.
    {
        const int c = tid;
        const int p = c & 15, q = c >> 4;
        float acc = 0.0f;
#pragma unroll
        for (int j = 0; j < RR; ++j)
            acc = fmaf(sR1[p][j], sQ[1][q][j], acc);
        T[u * 256 + c] = acc;
    }
}

// ---------------- kernel 2: batch evaluation ----------------

__global__ __launch_bounds__(256) void tree_eval(
    const float* __restrict__ X,
    const float* __restrict__ T,
    float* __restrict__ out)
{
    const int b0 = blockIdx.x * blockDim.x + threadIdx.x;  // 0..32767
    const int u0 = blockIdx.y * UPT;                       // block-uniform

    const float* __restrict__ Ta = T + (u0 + 0) * 256;     // wave-uniform
    const float* __restrict__ Tb = T + (u0 + 1) * 256;

    float w1[BPT][16], w2[BPT][16];
#pragma unroll
    for (int bt = 0; bt < BPT; ++bt) {
        const int b = b0 + bt * (BB / BPT);
        float x[FF][2];
        const float4* xp = reinterpret_cast<const float4*>(X + (size_t)b * (FF * DD));
#pragma unroll
        for (int qq = 0; qq < 4; ++qq) {
            float4 v = xp[qq];
            x[qq * 2 + 0][0] = v.x; x[qq * 2 + 0][1] = v.y;
            x[qq * 2 + 1][0] = v.z; x[qq * 2 + 1][1] = v.w;
        }
        float t01[4], t23[4], t45[4], t67[4];
#pragma unroll
        for (int a1 = 0; a1 < 2; ++a1)
#pragma unroll
            for (int a0 = 0; a0 < 2; ++a0) {
                t01[a1 * 2 + a0] = x[0][a0] * x[1][a1];
                t23[a1 * 2 + a0] = x[2][a0] * x[3][a1];
                t45[a1 * 2 + a0] = x[4][a0] * x[5][a1];
                t67[a1 * 2 + a0] = x[6][a0] * x[7][a1];
            }
#pragma unroll
        for (int p = 0; p < 16; ++p) {
            w1[bt][p] = t01[p & 3] * t23[p >> 2];
            w2[bt][p] = t45[p & 3] * t67[p >> 2];
        }
    }

    float accA[BPT], accB[BPT];
#pragma unroll
    for (int bt = 0; bt < BPT; ++bt) { accA[bt] = 0.0f; accB[bt] = 0.0f; }

#pragma unroll
    for (int q = 0; q < 16; ++q) {
        float sA[BPT], sB[BPT];
#pragma unroll
        for (int bt = 0; bt < BPT; ++bt) { sA[bt] = 0.0f; sB[bt] = 0.0f; }
#pragma unroll
        for (int p = 0; p < 16; ++p) {
            const float ta = Ta[q * 16 + p];   // scalar (u0 uniform)
            const float tb = Tb[q * 16 + p];
#pragma unroll
            for (int bt = 0; bt < BPT; ++bt) {
                sA[bt] = fmaf(ta, w1[bt][p], sA[bt]);
                sB[bt] = fmaf(tb, w1[bt][p], sB[bt]);
            }
        }
#pragma unroll
        for (int bt = 0; bt < BPT; ++bt) {
            accA[bt] = fmaf(w2[bt][q], sA[bt], accA[bt]);
            accB[bt] = fmaf(w2[bt][q], sB[bt], accB[bt]);
        }
    }

#pragma unroll
    for (int bt = 0; bt < BPT; ++bt) {
        const int b = b0 + bt * (BB / BPT);
        float2 o;
        o.x = accA[bt];
        o.y = accB[bt];
        *reinterpret_cast<float2*>(out + (size_t)b * UU + u0) = o;
    }
}

extern "C" void kernel_launch(void* const* d_in, const int* in_sizes, int n_in,
                              void* d_out, int out_size, void* d_ws, size_t ws_size,
                              hipStream_t stream) {
    const float* X      = (const float*)d_in[0];
    const float* core11 = (const float*)d_in[1];
    const float* core12 = (const float*)d_in[2];
    const float* core13 = (const float*)d_in[3];
    const float* core14 = (const float*)d_in[4];
    const float* core21 = (const float*)d_in[5];
    const float* core22 = (const float*)d_in[6];
    const float* FM     = (const float*)d_in[7];
    const float* MT     = (const float*)d_in[8];
    float* out          = (float*)d_out;
    float* T            = (float*)d_ws;   // 32*256*4 = 32 KB

    precompute_T_fast<<<dim3(UU), dim3(256), 0, stream>>>(
        core11, core12, core13, core14, core21, core22, FM, MT, T);

    tree_eval<<<dim3(BB / (256 * BPT), UU / UPT), dim3(256), 0, stream>>>(X, T, out);
}